// Round 5
// baseline (3846.190 us; speedup 1.0000x reference)
//
#include <hip/hip_runtime.h>
#include <math.h>

// ODE-RNN forward: B=1024, T=100, D=32, H=256, MID=50 (padded 64), RK4x4.
// Round 5: vectorize ALL reduce phases to float4 (partial phases unchanged
// from R4, which measured 0 bank conflicts / 0 spill). Scalar reduce loops
// were ~half the LDS instrs and most of the non-FMA VALU (addr math).
// Slot stride stays 5 f4 (20 floats): reduce reads land 8 bank-quads x 8
// distinct addrs = b128 conflict floor. Unrolled read offsets are constant.

#define NT 512

// ---------------- ws layout (floats), all packed-k float4 ----------------
#define WS_WCAT 0        // [72 g][256 j][4 c]  k=4g+c over concat [x(32); h(256)]
#define WS_L1P  73728    // [64 g][128 j][4 c]
#define WS_SW1  106496   // [64 g][256 j][4 c]
#define WS_TOT  172032

// ---------------- LDS layout (floats) ----------------
#define SM_PR1 0        // 512*20 partial slots
#define SM_PR2 10240    // 512*20
#define SM_H   20480    // [4][256] flat ([4][64] f4)
#define SM_YC  21504    // [4][256] (alias l1o[4][32] f4 in heads)
#define SM_AC  22528    // [4][256] (alias sg[4][64] f4 in heads)
#define SM_MD  23552    // [4][64]  ([4][16] f4)
#define SM_X4  23808    // [4][32]
#define SM_BC  23936    // 256
#define SM_OB1 24192    // 64
#define SM_OB2 24256    // 256
#define SM_L1B 24512    // 128
#define SM_SB1 24640    // 256
#define SM_MUW 24896    // 128
#define SM_SW2 25024    // 256
#define SM_SCL 25280    // 8
#define SM_TOT 25288
#define SMEM_BYTES (SM_TOT * 4)

__device__ __forceinline__ float fma4(float acc, float4 y, float4 w) {
  acc = fmaf(y.x, w.x, acc);
  acc = fmaf(y.y, w.y, acc);
  acc = fmaf(y.z, w.z, acc);
  acc = fmaf(y.w, w.w, acc);
  return acc;
}

__device__ __forceinline__ float4 add4(float4 a, float4 b) {
  return make_float4(a.x + b.x, a.y + b.y, a.z + b.z, a.w + b.w);
}

__device__ __forceinline__ float tfast(float x) {
  float ax = fabsf(x);
  float e  = __expf(-2.f * ax);
  float t  = (1.f - e) * __builtin_amdgcn_rcpf(1.f + e);
  return copysignf(t, x);
}

__device__ __forceinline__ float4 tfast4(float4 v) {
  return make_float4(tfast(v.x), tfast(v.y), tfast(v.z), tfast(v.w));
}

__global__ void prep_transpose(const float* __restrict__ Wih,
                               const float* __restrict__ Whh,
                               const float* __restrict__ l1w,
                               const float* __restrict__ sw1,
                               float* __restrict__ ws) {
  int i = blockIdx.x * 256 + threadIdx.x;
  if (i < 73728) {                       // Wcat4
    int g = i >> 10, rem = i & 1023, j = rem >> 2, c = rem & 3;
    int k = 4 * g + c;
    ws[i] = (k < 32) ? Wih[j * 32 + k] : Whh[j * 256 + (k - 32)];
  } else if (i < 106496) {               // l1p4
    int t = i - 73728;
    int g = t >> 9, rem = t & 511, j = rem >> 2, c = rem & 3;
    ws[i] = l1w[j * 256 + 4 * g + c];
  } else if (i < WS_TOT) {               // sw1p4
    int t = i - 106496;
    int g = t >> 10, rem = t & 1023, j = rem >> 2, c = rem & 3;
    ws[i] = sw1[j * 256 + 4 * g + c];
  }
}

__global__ __attribute__((amdgpu_flat_work_group_size(NT, NT)))
__attribute__((amdgpu_waves_per_eu(2)))
void odernn_main(const float* __restrict__ dt,
                 const float* __restrict__ x,
                 const float* __restrict__ bih,
                 const float* __restrict__ bhh,
                 const float* __restrict__ ow1,
                 const float* __restrict__ ob1g,
                 const float* __restrict__ ow2,
                 const float* __restrict__ ob2g,
                 const float* __restrict__ l1bg,
                 const float* __restrict__ muwg,
                 const float* __restrict__ mubg,
                 const float* __restrict__ sb1g,
                 const float* __restrict__ sw2g,
                 const float* __restrict__ sb2g,
                 const float* __restrict__ ws,
                 float* __restrict__ out) {
  extern __shared__ __align__(16) float sm[];
  const int tid = threadIdx.x;
  const int wv = tid >> 6, ln = tid & 63;
  const int b0 = blockIdx.x * 4;

  float* prS  = sm + SM_PR1;
  float* prS2 = sm + SM_PR2;
  float* hS   = sm + SM_H;
  float* ycS  = sm + SM_YC;
  float* acS  = sm + SM_AC;
  float* mdS  = sm + SM_MD;
  float* x4S  = sm + SM_X4;
  float* bcS  = sm + SM_BC;
  float* ob1S = sm + SM_OB1;
  float* ob2S = sm + SM_OB2;
  float* l1bS = sm + SM_L1B;
  float* sb1S = sm + SM_SB1;
  float* muwS = sm + SM_MUW;
  float* sw2S = sm + SM_SW2;
  float* sclS = sm + SM_SCL;

  float4* pr1_4 = (float4*)prS;
  float4* pr2_4 = (float4*)prS2;
  float4* h4   = (float4*)hS;    // [4][64]
  float4* yc4  = (float4*)ycS;   // [4][64]
  float4* ac4  = (float4*)acS;   // [4][64]
  float4* md4w = (float4*)mdS;   // [4][16]
  float4* l1o4 = (float4*)ycS;   // heads alias [4][32]
  float4* sg4  = (float4*)acS;   // heads alias [4][64]
  const float4* h44  = (const float4*)hS;
  const float4* yc44 = (const float4*)ycS;
  const float4* md4  = (const float4*)mdS;
  const float4* x44  = (const float4*)x4S;   // [4][8]
  const float4* bc4  = (const float4*)bcS;   // [64]
  const float4* ob1_4 = (const float4*)ob1S; // [16]
  const float4* ob2_4 = (const float4*)ob2S; // [64]
  const float4* l1b4 = (const float4*)l1bS;  // [32]
  const float4* sb14 = (const float4*)sb1S;  // [64]
  const float4* muw4 = (const float4*)muwS;  // [32]
  const float4* sw24 = (const float4*)sw2S;  // [64]

  const float4* wcat4 = (const float4*)(ws + WS_WCAT); // f4 idx g*256 + j
  const float4* l1w4  = (const float4*)(ws + WS_L1P);  // f4 idx g*128 + j
  const float4* sw14  = (const float4*)(ws + WS_SW1);  // f4 idx g*256 + j

  // ---- persistent ODE weight registers (64 VGPRs total, no duplication)
  const int q1 = tid & 15, kc1 = tid >> 4;          // kc1 in [0,32)
  const int cq2 = tid & 63, kc2 = tid >> 6;         // kc2 in [0,8)
  float4 w1r[4][2];
  float4 w2r[4][2];
  {
#pragma unroll
    for (int n = 0; n < 4; ++n) {
      int row = 4 * q1 + n;
#pragma unroll
      for (int g = 0; g < 2; ++g) {
        if (row < 50)
          w1r[n][g] = *(const float4*)&ow1[row * 256 + kc1 * 8 + 4 * g];
        else
          w1r[n][g] = make_float4(0.f, 0.f, 0.f, 0.f);
      }
    }
    float w2tmp[4];
#pragma unroll
    for (int n = 0; n < 4; ++n) {
      int col = 4 * cq2 + n;
#pragma unroll
      for (int g = 0; g < 2; ++g) {
#pragma unroll
        for (int c = 0; c < 4; ++c) {
          int k = kc2 * 8 + 4 * g + c;
          w2tmp[c] = (k < 50) ? ow2[col * 50 + k] : 0.f;
        }
        w2r[n][g] = make_float4(w2tmp[0], w2tmp[1], w2tmp[2], w2tmp[3]);
      }
    }
  }

  // ---- one-time staging
  if (tid < 256) {
    bcS[tid]  = bih[tid] + bhh[tid];
    ob2S[tid] = ob2g[tid];
    sb1S[tid] = sb1g[tid];
    sw2S[tid] = sw2g[tid];
  }
  if (tid < 64)  ob1S[tid] = (tid < 50) ? ob1g[tid] : 0.f;
  if (tid < 128) { l1bS[tid] = l1bg[tid]; muwS[tid] = muwg[tid]; }
  hS[tid] = 0.f; hS[tid + 512] = 0.f;
  __syncthreads();

  const float mub = mubg[0], sb2 = sb2g[0];

  for (int t = 0; t < 100; ++t) {
    // ---- stage x tile and per-row scale
    if (tid < 128) {
      int r = tid >> 5, kk = tid & 31;
      x4S[r * 32 + kk] = x[((size_t)(b0 + r) * 100 + t) * 32 + kk];
    }
    if (tid < 4) {
      const float* dp = dt + ((size_t)(b0 + tid) * 100 + t) * 2;
      sclS[tid] = (dp[1] - dp[0]) * (1.f / 24.f);
    }
    __syncthreads();

    // ===== RNN partials: K=288 concat, (jq 64, kc 8), 4 cols x 4 rows
    {
      const int jq = tid & 63, kc = tid >> 6;
      float4 acc0 = make_float4(0, 0, 0, 0), acc1 = acc0, acc2 = acc0, acc3 = acc0;
#pragma unroll 3
      for (int gg = 0; gg < 9; ++gg) {
        int g = kc * 9 + gg;                         // k = 4g
        float4 w0 = wcat4[g * 256 + 4 * jq + 0];
        float4 w1 = wcat4[g * 256 + 4 * jq + 1];
        float4 w2 = wcat4[g * 256 + 4 * jq + 2];
        float4 w3 = wcat4[g * 256 + 4 * jq + 3];
        float4 y0 = (g < 8) ? x44[0 * 8 + g] : h44[0 * 64 + (g - 8)];
        float4 y1 = (g < 8) ? x44[1 * 8 + g] : h44[1 * 64 + (g - 8)];
        float4 y2 = (g < 8) ? x44[2 * 8 + g] : h44[2 * 64 + (g - 8)];
        float4 y3 = (g < 8) ? x44[3 * 8 + g] : h44[3 * 64 + (g - 8)];
        acc0.x = fma4(acc0.x, y0, w0); acc0.y = fma4(acc0.y, y0, w1);
        acc0.z = fma4(acc0.z, y0, w2); acc0.w = fma4(acc0.w, y0, w3);
        acc1.x = fma4(acc1.x, y1, w0); acc1.y = fma4(acc1.y, y1, w1);
        acc1.z = fma4(acc1.z, y1, w2); acc1.w = fma4(acc1.w, y1, w3);
        acc2.x = fma4(acc2.x, y2, w0); acc2.y = fma4(acc2.y, y2, w1);
        acc2.z = fma4(acc2.z, y2, w2); acc2.w = fma4(acc2.w, y2, w3);
        acc3.x = fma4(acc3.x, y3, w0); acc3.y = fma4(acc3.y, y3, w1);
        acc3.z = fma4(acc3.z, y3, w2); acc3.w = fma4(acc3.w, y3, w3);
      }
      pr1_4[tid * 5 + 0] = acc0;   // slot tid = kc*64 + jq, comp = row
      pr1_4[tid * 5 + 1] = acc1;
      pr1_4[tid * 5 + 2] = acc2;
      pr1_4[tid * 5 + 3] = acc3;
    }
    __syncthreads();
    // ===== RNN reduce (f4): 256 thr, outQ = (r, jq)
    if (tid < 256) {
      const int r = tid >> 6, jq = tid & 63;
      const float4* base = pr1_4 + (jq * 5 + r);
      float4 v = base[0];
#pragma unroll
      for (int kc = 1; kc < 8; ++kc) v = add4(v, base[kc * 320]);
      v = add4(v, bc4[jq]);
      int o4 = r * 64 + jq;
      h4[o4] = add4(h4[o4], tfast4(v));
    }
    __syncthreads();

    // ===== ODE: 4 RK4 steps, hs = 0.25
#pragma unroll 1
    for (int os = 0; os < 4; ++os) {
#pragma unroll
      for (int s = 0; s < 4; ++s) {
        // --- L1 partials: f4 = 4 neurons (4q1..+3), one row per comp
        {
          const float4* ysrc = (s == 0) ? h44 : yc44;
          float4 a0 = make_float4(0, 0, 0, 0), a1 = a0, a2 = a0, a3 = a0;
#pragma unroll
          for (int g = 0; g < 2; ++g) {
            float4 y0 = ysrc[0 * 64 + kc1 * 2 + g];
            float4 y1 = ysrc[1 * 64 + kc1 * 2 + g];
            float4 y2 = ysrc[2 * 64 + kc1 * 2 + g];
            float4 y3 = ysrc[3 * 64 + kc1 * 2 + g];
            a0.x = fma4(a0.x, y0, w1r[0][g]); a0.y = fma4(a0.y, y0, w1r[1][g]);
            a0.z = fma4(a0.z, y0, w1r[2][g]); a0.w = fma4(a0.w, y0, w1r[3][g]);
            a1.x = fma4(a1.x, y1, w1r[0][g]); a1.y = fma4(a1.y, y1, w1r[1][g]);
            a1.z = fma4(a1.z, y1, w1r[2][g]); a1.w = fma4(a1.w, y1, w1r[3][g]);
            a2.x = fma4(a2.x, y2, w1r[0][g]); a2.y = fma4(a2.y, y2, w1r[1][g]);
            a2.z = fma4(a2.z, y2, w1r[2][g]); a2.w = fma4(a2.w, y2, w1r[3][g]);
            a3.x = fma4(a3.x, y3, w1r[0][g]); a3.y = fma4(a3.y, y3, w1r[1][g]);
            a3.z = fma4(a3.z, y3, w1r[2][g]); a3.w = fma4(a3.w, y3, w1r[3][g]);
          }
          pr1_4[tid * 5 + 0] = a0;   // slot tid = kc1*16 + q1
          pr1_4[tid * 5 + 1] = a1;
          pr1_4[tid * 5 + 2] = a2;
          pr1_4[tid * 5 + 3] = a3;
        }
        __syncthreads();
        // --- L1 reduce (f4): 256 thr, (outQ = r*16+q, sub in 4)
        if (tid < 256) {
          const int r = tid >> 6, qr = (tid >> 2) & 15, sub = tid & 3;
          const float4* base = pr1_4 + ((sub * 16 + qr) * 5 + r);
          float4 v = base[0];
#pragma unroll
          for (int i = 1; i < 8; ++i) v = add4(v, base[i * 320]);
          v.x += __shfl_xor(v.x, 1); v.y += __shfl_xor(v.y, 1);
          v.z += __shfl_xor(v.z, 1); v.w += __shfl_xor(v.w, 1);
          v.x += __shfl_xor(v.x, 2); v.y += __shfl_xor(v.y, 2);
          v.z += __shfl_xor(v.z, 2); v.w += __shfl_xor(v.w, 2);
          if (sub == 0)
            md4w[r * 16 + qr] = tfast4(add4(v, ob1_4[qr]));
        }
        __syncthreads();
        // --- L2 partials: f4 = 4 cols (4cq2..+3), one row per comp
        {
          float4 b0v = make_float4(0, 0, 0, 0), b1v = b0v, b2v = b0v, b3v = b0v;
#pragma unroll
          for (int g = 0; g < 2; ++g) {
            float4 m0 = md4[0 * 16 + kc2 * 2 + g];
            float4 m1 = md4[1 * 16 + kc2 * 2 + g];
            float4 m2 = md4[2 * 16 + kc2 * 2 + g];
            float4 m3 = md4[3 * 16 + kc2 * 2 + g];
            b0v.x = fma4(b0v.x, m0, w2r[0][g]); b0v.y = fma4(b0v.y, m0, w2r[1][g]);
            b0v.z = fma4(b0v.z, m0, w2r[2][g]); b0v.w = fma4(b0v.w, m0, w2r[3][g]);
            b1v.x = fma4(b1v.x, m1, w2r[0][g]); b1v.y = fma4(b1v.y, m1, w2r[1][g]);
            b1v.z = fma4(b1v.z, m1, w2r[2][g]); b1v.w = fma4(b1v.w, m1, w2r[3][g]);
            b2v.x = fma4(b2v.x, m2, w2r[0][g]); b2v.y = fma4(b2v.y, m2, w2r[1][g]);
            b2v.z = fma4(b2v.z, m2, w2r[2][g]); b2v.w = fma4(b2v.w, m2, w2r[3][g]);
            b3v.x = fma4(b3v.x, m3, w2r[0][g]); b3v.y = fma4(b3v.y, m3, w2r[1][g]);
            b3v.z = fma4(b3v.z, m3, w2r[2][g]); b3v.w = fma4(b3v.w, m3, w2r[3][g]);
          }
          pr2_4[tid * 5 + 0] = b0v;  // slot tid = kc2*64 + cq2
          pr2_4[tid * 5 + 1] = b1v;
          pr2_4[tid * 5 + 2] = b2v;
          pr2_4[tid * 5 + 3] = b3v;
        }
        __syncthreads();
        // --- L2 reduce + RK4 (f4): 256 thr, outQ = (r, cq)
        if (tid < 256) {
          const int r = tid >> 6, cq = tid & 63;
          const float4* base = pr2_4 + (cq * 5 + r);
          float4 v = base[0];
#pragma unroll
          for (int kc = 1; kc < 8; ++kc) v = add4(v, base[kc * 320]);
          v = add4(v, ob2_4[cq]);
          float sc = sclS[r];
          float4 kv = make_float4(v.x * sc, v.y * sc, v.z * sc, v.w * sc);
          int o4 = r * 64 + cq;
          if (s == 0) {
            ac4[o4] = kv;
            float4 hv = h4[o4];
            yc4[o4] = make_float4(hv.x + 0.125f * kv.x, hv.y + 0.125f * kv.y,
                                  hv.z + 0.125f * kv.z, hv.w + 0.125f * kv.w);
          } else if (s == 1) {
            float4 a = ac4[o4];
            ac4[o4] = make_float4(a.x + 2.f * kv.x, a.y + 2.f * kv.y,
                                  a.z + 2.f * kv.z, a.w + 2.f * kv.w);
            float4 hv = h4[o4];
            yc4[o4] = make_float4(hv.x + 0.125f * kv.x, hv.y + 0.125f * kv.y,
                                  hv.z + 0.125f * kv.z, hv.w + 0.125f * kv.w);
          } else if (s == 2) {
            float4 a = ac4[o4];
            ac4[o4] = make_float4(a.x + 2.f * kv.x, a.y + 2.f * kv.y,
                                  a.z + 2.f * kv.z, a.w + 2.f * kv.w);
            float4 hv = h4[o4];
            yc4[o4] = make_float4(hv.x + 0.25f * kv.x, hv.y + 0.25f * kv.y,
                                  hv.z + 0.25f * kv.z, hv.w + 0.25f * kv.w);
          } else {
            float4 a = ac4[o4];
            float4 hv = h4[o4];
            const float c6 = 0.25f / 6.f;
            h4[o4] = make_float4(hv.x + c6 * (a.x + kv.x), hv.y + c6 * (a.y + kv.y),
                                 hv.z + c6 * (a.z + kv.z), hv.w + c6 * (a.w + kv.w));
          }
        }
        __syncthreads();
      }
    }

    // ===== heads
    // l1 partials: (cq 32, kc 16): 4 cols x 4 rows x 16 k  -> prS
    {
      const int cq = tid & 31, kc = tid >> 5;
      float4 c0 = make_float4(0, 0, 0, 0), c1 = c0, c2 = c0, c3 = c0;
#pragma unroll 2
      for (int g = 0; g < 4; ++g) {
        int kg = kc * 4 + g;
        float4 w0 = l1w4[kg * 128 + 4 * cq + 0];
        float4 w1 = l1w4[kg * 128 + 4 * cq + 1];
        float4 w2 = l1w4[kg * 128 + 4 * cq + 2];
        float4 w3 = l1w4[kg * 128 + 4 * cq + 3];
        float4 y0 = h44[0 * 64 + kg], y1 = h44[1 * 64 + kg];
        float4 y2 = h44[2 * 64 + kg], y3 = h44[3 * 64 + kg];
        c0.x = fma4(c0.x, y0, w0); c0.y = fma4(c0.y, y0, w1);
        c0.z = fma4(c0.z, y0, w2); c0.w = fma4(c0.w, y0, w3);
        c1.x = fma4(c1.x, y1, w0); c1.y = fma4(c1.y, y1, w1);
        c1.z = fma4(c1.z, y1, w2); c1.w = fma4(c1.w, y1, w3);
        c2.x = fma4(c2.x, y2, w0); c2.y = fma4(c2.y, y2, w1);
        c2.z = fma4(c2.z, y2, w2); c2.w = fma4(c2.w, y2, w3);
        c3.x = fma4(c3.x, y3, w0); c3.y = fma4(c3.y, y3, w1);
        c3.z = fma4(c3.z, y3, w2); c3.w = fma4(c3.w, y3, w3);
      }
      pr1_4[tid * 5 + 0] = c0;   // slot tid = kc*32 + cq
      pr1_4[tid * 5 + 1] = c1;
      pr1_4[tid * 5 + 2] = c2;
      pr1_4[tid * 5 + 3] = c3;
    }
    // sig1 partials: (cq 64, kc 8): 4 cols x 4 rows x 32 k  -> prS2
    {
      const int cq = tid & 63, kc = tid >> 6;
      float4 d0 = make_float4(0, 0, 0, 0), d1 = d0, d2 = d0, d3 = d0;
#pragma unroll 2
      for (int g = 0; g < 8; ++g) {
        int kg = kc * 8 + g;
        float4 w0 = sw14[kg * 256 + 4 * cq + 0];
        float4 w1 = sw14[kg * 256 + 4 * cq + 1];
        float4 w2 = sw14[kg * 256 + 4 * cq + 2];
        float4 w3 = sw14[kg * 256 + 4 * cq + 3];
        float4 y0 = h44[0 * 64 + kg], y1 = h44[1 * 64 + kg];
        float4 y2 = h44[2 * 64 + kg], y3 = h44[3 * 64 + kg];
        d0.x = fma4(d0.x, y0, w0); d0.y = fma4(d0.y, y0, w1);
        d0.z = fma4(d0.z, y0, w2); d0.w = fma4(d0.w, y0, w3);
        d1.x = fma4(d1.x, y1, w0); d1.y = fma4(d1.y, y1, w1);
        d1.z = fma4(d1.z, y1, w2); d1.w = fma4(d1.w, y1, w3);
        d2.x = fma4(d2.x, y2, w0); d2.y = fma4(d2.y, y2, w1);
        d2.z = fma4(d2.z, y2, w2); d2.w = fma4(d2.w, y2, w3);
        d3.x = fma4(d3.x, y3, w0); d3.y = fma4(d3.y, y3, w1);
        d3.z = fma4(d3.z, y3, w2); d3.w = fma4(d3.w, y3, w3);
      }
      pr2_4[tid * 5 + 0] = d0;   // slot tid = kc*64 + cq
      pr2_4[tid * 5 + 1] = d1;
      pr2_4[tid * 5 + 2] = d2;
      pr2_4[tid * 5 + 3] = d3;
    }
    __syncthreads();
    // head reduces (f4), one phase: l1 on tid<256, sig1 on tid>=256
    if (tid < 256) {
      const int outQ = tid >> 1, sub = tid & 1;
      const int r = outQ >> 5, cq = outQ & 31;
      const float4* base = pr1_4 + ((sub * 32 + cq) * 5 + r);
      float4 v = base[0];
#pragma unroll
      for (int i = 1; i < 8; ++i) v = add4(v, base[i * 320]);   // kc=sub+2i
      v.x += __shfl_xor(v.x, 1); v.y += __shfl_xor(v.y, 1);
      v.z += __shfl_xor(v.z, 1); v.w += __shfl_xor(v.w, 1);
      if (sub == 0) {
        float4 b = l1b4[cq];
        l1o4[r * 32 + cq] = make_float4(fmaxf(v.x + b.x, 0.f), fmaxf(v.y + b.y, 0.f),
                                        fmaxf(v.z + b.z, 0.f), fmaxf(v.w + b.w, 0.f));
      }
    } else {
      const int t2 = tid & 255;
      const int r = t2 >> 6, cq = t2 & 63;
      const float4* base = pr2_4 + (cq * 5 + r);
      float4 v = base[0];
#pragma unroll
      for (int kc = 1; kc < 8; ++kc) v = add4(v, base[kc * 320]);
      sg4[r * 64 + cq] = tfast4(add4(v, sb14[cq]));
    }
    __syncthreads();
    // final dot-products: waves 0-3 -> mu rows, waves 4-7 -> sig rows
    {
      if (wv < 4) {
        const int r = wv, c = ln & 31;
        float4 l = l1o4[r * 32 + c], w = muw4[c];
        float pm = (ln < 32) ? (l.x * w.x + l.y * w.y + l.z * w.z + l.w * w.w) : 0.f;
#pragma unroll
        for (int off = 32; off > 0; off >>= 1) pm += __shfl_down(pm, off);
        if (ln == 0) out[(size_t)(b0 + r) * 100 + t] = pm + mub;
      } else {
        const int r = wv - 4;
        float4 s4 = sg4[r * 64 + ln], w = sw24[ln];
        float ps = s4.x * w.x + s4.y * w.y + s4.z * w.z + s4.w * w.w;
#pragma unroll
        for (int off = 32; off > 0; off >>= 1) ps += __shfl_down(ps, off);
        if (ln == 0) {
          float z = ps + sb2;
          float sp = fmaxf(z, 0.f) + log1pf(expf(-fabsf(z)));
          out[(size_t)102400 + (size_t)(b0 + r) * 100 + t] = sp;
        }
      }
    }
    // no barrier: next-step staging writes x4S/sclS, disjoint from l1o/sg
  }
}

extern "C" void kernel_launch(void* const* d_in, const int* in_sizes, int n_in,
                              void* d_out, int out_size, void* d_ws, size_t ws_size,
                              hipStream_t stream) {
  const float* dt  = (const float*)d_in[0];
  const float* x   = (const float*)d_in[1];
  const float* Wih = (const float*)d_in[2];
  const float* bih = (const float*)d_in[3];
  const float* Whh = (const float*)d_in[4];
  const float* bhh = (const float*)d_in[5];
  const float* ow1 = (const float*)d_in[6];
  const float* ob1 = (const float*)d_in[7];
  const float* ow2 = (const float*)d_in[8];
  const float* ob2 = (const float*)d_in[9];
  const float* l1w = (const float*)d_in[10];
  const float* l1b = (const float*)d_in[11];
  const float* muw = (const float*)d_in[12];
  const float* mub = (const float*)d_in[13];
  const float* sw1 = (const float*)d_in[14];
  const float* sb1 = (const float*)d_in[15];
  const float* sw2 = (const float*)d_in[16];
  const float* sb2 = (const float*)d_in[17];
  float* ws  = (float*)d_ws;
  float* out = (float*)d_out;

  hipFuncSetAttribute((const void*)odernn_main,
                      hipFuncAttributeMaxDynamicSharedMemorySize, SMEM_BYTES);

  prep_transpose<<<WS_TOT / 256, 256, 0, stream>>>(Wih, Whh, l1w, sw1, ws);
  odernn_main<<<256, NT, SMEM_BYTES, stream>>>(dt, x, bih, bhh, ow1, ob1, ow2, ob2,
                                               l1b, muw, mub, sb1, sw2, sb2, ws, out);
}

// Round 6
// 3755.473 us; speedup vs baseline: 1.0242x; 1.0242x over previous
//
#include <hip/hip_runtime.h>
#include <math.h>

// ODE-RNN forward: B=1024, T=100, D=32, H=256, MID=50 (padded 64), RK4x4.
// Round 6: (a) conflict-free partial layout pr[kc][r][lane] -- every b128
// write/read is lane-contiguous 16B (consecutive 8-lane groups cover 8
// distinct bank quads); (b) 512 blocks x 2 rows x 512 thr, LDS 45KB ->
// 2 blocks/CU (16 waves/CU), two independent barrier domains per CU to
// overlap the phase latency that dominated R4/R5.

#define NT 512

// ---------------- ws layout (floats), all packed-k float4 ----------------
#define WS_WCAT 0        // [72 g][256 j][4 c]  k=4g+c over concat [x(32); h(256)]
#define WS_L1P  73728    // [64 g][128 j][4 c]
#define WS_SW1  106496   // [64 g][256 j][4 c]
#define WS_TOT  172032

// ---------------- LDS layout (floats) ----------------
#define SM_PR  0        // 2048 f4 = 8192 floats (shared by all partial phases)
#define SM_H   8192     // [2][256]
#define SM_YC  8704     // [2][256] (alias l1o [2][32] f4)
#define SM_AC  9216     // [2][256] (alias sg  [2][64] f4)
#define SM_MD  9728     // [2][64]
#define SM_X4  9856     // [2][32]
#define SM_BC  9920     // 256
#define SM_OB1 10176    // 64
#define SM_OB2 10240    // 256
#define SM_L1B 10496    // 128
#define SM_SB1 10624    // 256
#define SM_MUW 10880    // 128
#define SM_SW2 11008    // 256
#define SM_SCL 11264    // 8
#define SM_TOT 11272
#define SMEM_BYTES (SM_TOT * 4)

__device__ __forceinline__ float fma4(float acc, float4 y, float4 w) {
  acc = fmaf(y.x, w.x, acc);
  acc = fmaf(y.y, w.y, acc);
  acc = fmaf(y.z, w.z, acc);
  acc = fmaf(y.w, w.w, acc);
  return acc;
}

__device__ __forceinline__ float4 add4(float4 a, float4 b) {
  return make_float4(a.x + b.x, a.y + b.y, a.z + b.z, a.w + b.w);
}

__device__ __forceinline__ float tfast(float x) {
  float ax = fabsf(x);
  float e  = __expf(-2.f * ax);
  float t  = (1.f - e) * __builtin_amdgcn_rcpf(1.f + e);
  return copysignf(t, x);
}

__device__ __forceinline__ float4 tfast4(float4 v) {
  return make_float4(tfast(v.x), tfast(v.y), tfast(v.z), tfast(v.w));
}

__global__ void prep_transpose(const float* __restrict__ Wih,
                               const float* __restrict__ Whh,
                               const float* __restrict__ l1w,
                               const float* __restrict__ sw1,
                               float* __restrict__ ws) {
  int i = blockIdx.x * 256 + threadIdx.x;
  if (i < 73728) {                       // Wcat4
    int g = i >> 10, rem = i & 1023, j = rem >> 2, c = rem & 3;
    int k = 4 * g + c;
    ws[i] = (k < 32) ? Wih[j * 32 + k] : Whh[j * 256 + (k - 32)];
  } else if (i < 106496) {               // l1p4
    int t = i - 73728;
    int g = t >> 9, rem = t & 511, j = rem >> 2, c = rem & 3;
    ws[i] = l1w[j * 256 + 4 * g + c];
  } else if (i < WS_TOT) {               // sw1p4
    int t = i - 106496;
    int g = t >> 10, rem = t & 1023, j = rem >> 2, c = rem & 3;
    ws[i] = sw1[j * 256 + 4 * g + c];
  }
}

__global__ __attribute__((amdgpu_flat_work_group_size(NT, NT)))
__attribute__((amdgpu_waves_per_eu(4)))
void odernn_main(const float* __restrict__ dt,
                 const float* __restrict__ x,
                 const float* __restrict__ bih,
                 const float* __restrict__ bhh,
                 const float* __restrict__ ow1,
                 const float* __restrict__ ob1g,
                 const float* __restrict__ ow2,
                 const float* __restrict__ ob2g,
                 const float* __restrict__ l1bg,
                 const float* __restrict__ muwg,
                 const float* __restrict__ mubg,
                 const float* __restrict__ sb1g,
                 const float* __restrict__ sw2g,
                 const float* __restrict__ sb2g,
                 const float* __restrict__ ws,
                 float* __restrict__ out) {
  extern __shared__ __align__(16) float sm[];
  const int tid = threadIdx.x;
  const int wv = tid >> 6, ln = tid & 63;
  const int b0 = blockIdx.x * 2;                  // 2 rows per block

  float* hS   = sm + SM_H;
  float* x4S  = sm + SM_X4;
  float* bcS  = sm + SM_BC;
  float* ob1S = sm + SM_OB1;
  float* ob2S = sm + SM_OB2;
  float* l1bS = sm + SM_L1B;
  float* sb1S = sm + SM_SB1;
  float* muwS = sm + SM_MUW;
  float* sw2S = sm + SM_SW2;
  float* sclS = sm + SM_SCL;

  float4* pr4  = (float4*)(sm + SM_PR);      // 2048 f4
  float4* h4   = (float4*)(sm + SM_H);       // [2][64]
  float4* yc4  = (float4*)(sm + SM_YC);      // [2][64]
  float4* ac4  = (float4*)(sm + SM_AC);      // [2][64]
  float4* md4w = (float4*)(sm + SM_MD);      // [2][16]
  float4* l1o4 = (float4*)(sm + SM_YC);      // heads alias [2][32]
  float4* sg4  = (float4*)(sm + SM_AC);      // heads alias [2][64]
  const float4* h44  = (const float4*)(sm + SM_H);
  const float4* yc44 = (const float4*)(sm + SM_YC);
  const float4* md4  = (const float4*)(sm + SM_MD);
  const float4* x44  = (const float4*)(sm + SM_X4);   // [2][8]
  const float4* bc4  = (const float4*)bcS;    // [64]
  const float4* ob1_4 = (const float4*)ob1S;  // [16]
  const float4* ob2_4 = (const float4*)ob2S;  // [64]
  const float4* l1b4 = (const float4*)l1bS;   // [32]
  const float4* sb14 = (const float4*)sb1S;   // [64]
  const float4* muw4 = (const float4*)muwS;   // [32]
  const float4* sw24 = (const float4*)sw2S;   // [64]

  const float4* wcat4 = (const float4*)(ws + WS_WCAT); // f4 idx g*256 + j
  const float4* l1w4  = (const float4*)(ws + WS_L1P);  // f4 idx g*128 + j
  const float4* sw14  = (const float4*)(ws + WS_SW1);  // f4 idx g*256 + j

  // ---- persistent ODE weight registers (64 VGPRs, no duplication)
  // L1: (q1 = tid&15, kc1 = tid>>4 in [0,32)): neurons 4q1..+3, k in [8kc1,8kc1+8)
  // L2: (cq2 = tid&63, kc2 = tid>>6 in [0,8)): cols 4cq2..+3,  k in [8kc2,8kc2+8)
  const int q1 = tid & 15, kc1 = tid >> 4;
  const int cq2 = tid & 63, kc2 = tid >> 6;
  float4 w1r[4][2];
  float4 w2r[4][2];
  {
#pragma unroll
    for (int n = 0; n < 4; ++n) {
      int row = 4 * q1 + n;
#pragma unroll
      for (int g = 0; g < 2; ++g) {
        if (row < 50)
          w1r[n][g] = *(const float4*)&ow1[row * 256 + kc1 * 8 + 4 * g];
        else
          w1r[n][g] = make_float4(0.f, 0.f, 0.f, 0.f);
      }
    }
    float w2tmp[4];
#pragma unroll
    for (int n = 0; n < 4; ++n) {
      int col = 4 * cq2 + n;
#pragma unroll
      for (int g = 0; g < 2; ++g) {
#pragma unroll
        for (int c = 0; c < 4; ++c) {
          int k = kc2 * 8 + 4 * g + c;
          w2tmp[c] = (k < 50) ? ow2[col * 50 + k] : 0.f;
        }
        w2r[n][g] = make_float4(w2tmp[0], w2tmp[1], w2tmp[2], w2tmp[3]);
      }
    }
  }

  // ---- one-time staging
  if (tid < 256) {
    bcS[tid]  = bih[tid] + bhh[tid];
    ob2S[tid] = ob2g[tid];
    sb1S[tid] = sb1g[tid];
    sw2S[tid] = sw2g[tid];
  }
  if (tid < 64)  ob1S[tid] = (tid < 50) ? ob1g[tid] : 0.f;
  if (tid < 128) { l1bS[tid] = l1bg[tid]; muwS[tid] = muwg[tid]; }
  if (tid < 512) hS[tid] = 0.f;
  __syncthreads();

  const float mub = mubg[0], sb2 = sb2g[0];

  for (int t = 0; t < 100; ++t) {
    // ---- stage x tile (2 rows) and per-row scale
    if (tid < 64) {
      int r = tid >> 5, kk = tid & 31;
      x4S[r * 32 + kk] = x[((size_t)(b0 + r) * 100 + t) * 32 + kk];
    }
    if (tid < 2) {
      const float* dp = dt + ((size_t)(b0 + tid) * 100 + t) * 2;
      sclS[tid] = (dp[1] - dp[0]) * (1.f / 24.f);
    }
    __syncthreads();

    // ===== RNN partials: K=288 concat, (jq 64, kc 8), 4 cols x 2 rows
    {
      const int jq = tid & 63, kc = tid >> 6;
      float4 acc0 = make_float4(0, 0, 0, 0), acc1 = acc0;
#pragma unroll 3
      for (int gg = 0; gg < 9; ++gg) {
        int g = kc * 9 + gg;                         // k = 4g
        float4 w0 = wcat4[g * 256 + 4 * jq + 0];
        float4 w1 = wcat4[g * 256 + 4 * jq + 1];
        float4 w2 = wcat4[g * 256 + 4 * jq + 2];
        float4 w3 = wcat4[g * 256 + 4 * jq + 3];
        float4 y0 = (g < 8) ? x44[g]     : h44[g - 8];
        float4 y1 = (g < 8) ? x44[8 + g] : h44[64 + (g - 8)];
        acc0.x = fma4(acc0.x, y0, w0); acc0.y = fma4(acc0.y, y0, w1);
        acc0.z = fma4(acc0.z, y0, w2); acc0.w = fma4(acc0.w, y0, w3);
        acc1.x = fma4(acc1.x, y1, w0); acc1.y = fma4(acc1.y, y1, w1);
        acc1.z = fma4(acc1.z, y1, w2); acc1.w = fma4(acc1.w, y1, w3);
      }
      pr4[(kc * 2 + 0) * 64 + jq] = acc0;   // [kc][r][jq] lane-contiguous
      pr4[(kc * 2 + 1) * 64 + jq] = acc1;
    }
    __syncthreads();
    // ===== RNN reduce (f4): 128 thr, (r, jq), lane-contiguous reads
    if (tid < 128) {
      const int r = tid >> 6, jq = tid & 63;
      float4 v = pr4[r * 64 + jq];
#pragma unroll
      for (int kc = 1; kc < 8; ++kc) v = add4(v, pr4[(kc * 2 + r) * 64 + jq]);
      v = add4(v, bc4[jq]);
      int o4 = r * 64 + jq;
      h4[o4] = add4(h4[o4], tfast4(v));
    }
    __syncthreads();

    // ===== ODE: 4 RK4 steps, hs = 0.25
#pragma unroll 1
    for (int os = 0; os < 4; ++os) {
#pragma unroll
      for (int s = 0; s < 4; ++s) {
        // --- L1 partials: f4 = 4 neurons, store [kc1][r][q1]
        {
          const float4* ysrc = (s == 0) ? h44 : yc44;
          float4 a0 = make_float4(0, 0, 0, 0), a1 = a0;
#pragma unroll
          for (int g = 0; g < 2; ++g) {
            float4 y0 = ysrc[kc1 * 2 + g];          // row 0 (broadcast)
            float4 y1 = ysrc[64 + kc1 * 2 + g];     // row 1
            a0.x = fma4(a0.x, y0, w1r[0][g]); a0.y = fma4(a0.y, y0, w1r[1][g]);
            a0.z = fma4(a0.z, y0, w1r[2][g]); a0.w = fma4(a0.w, y0, w1r[3][g]);
            a1.x = fma4(a1.x, y1, w1r[0][g]); a1.y = fma4(a1.y, y1, w1r[1][g]);
            a1.z = fma4(a1.z, y1, w1r[2][g]); a1.w = fma4(a1.w, y1, w1r[3][g]);
          }
          pr4[(kc1 * 2 + 0) * 16 + q1] = a0;
          pr4[(kc1 * 2 + 1) * 16 + q1] = a1;
        }
        __syncthreads();
        // --- L1 reduce: 128 thr (r = wave, lanes = sub*16+q1), shfl over sub
        if (tid < 128) {
          const int r = tid >> 6, sub = (tid >> 4) & 3, qq = tid & 15;
          float4 v = pr4[(sub * 8 * 2 + r) * 16 + qq];
#pragma unroll
          for (int i = 1; i < 8; ++i)
            v = add4(v, pr4[((sub * 8 + i) * 2 + r) * 16 + qq]);
          v.x += __shfl_xor(v.x, 16); v.y += __shfl_xor(v.y, 16);
          v.z += __shfl_xor(v.z, 16); v.w += __shfl_xor(v.w, 16);
          v.x += __shfl_xor(v.x, 32); v.y += __shfl_xor(v.y, 32);
          v.z += __shfl_xor(v.z, 32); v.w += __shfl_xor(v.w, 32);
          if (sub == 0)
            md4w[r * 16 + qq] = tfast4(add4(v, ob1_4[qq]));
        }
        __syncthreads();
        // --- L2 partials: f4 = 4 cols, store [kc2][r][cq2]
        {
          float4 b0v = make_float4(0, 0, 0, 0), b1v = b0v;
#pragma unroll
          for (int g = 0; g < 2; ++g) {
            float4 m0 = md4[kc2 * 2 + g];           // row 0 (broadcast)
            float4 m1 = md4[16 + kc2 * 2 + g];      // row 1
            b0v.x = fma4(b0v.x, m0, w2r[0][g]); b0v.y = fma4(b0v.y, m0, w2r[1][g]);
            b0v.z = fma4(b0v.z, m0, w2r[2][g]); b0v.w = fma4(b0v.w, m0, w2r[3][g]);
            b1v.x = fma4(b1v.x, m1, w2r[0][g]); b1v.y = fma4(b1v.y, m1, w2r[1][g]);
            b1v.z = fma4(b1v.z, m1, w2r[2][g]); b1v.w = fma4(b1v.w, m1, w2r[3][g]);
          }
          pr4[(kc2 * 2 + 0) * 64 + cq2] = b0v;
          pr4[(kc2 * 2 + 1) * 64 + cq2] = b1v;
        }
        __syncthreads();
        // --- L2 reduce + RK4 (f4): 128 thr, (r, cq), lane-contiguous
        if (tid < 128) {
          const int r = tid >> 6, cq = tid & 63;
          float4 v = pr4[r * 64 + cq];
#pragma unroll
          for (int kc = 1; kc < 8; ++kc) v = add4(v, pr4[(kc * 2 + r) * 64 + cq]);
          v = add4(v, ob2_4[cq]);
          float sc = sclS[r];
          float4 kv = make_float4(v.x * sc, v.y * sc, v.z * sc, v.w * sc);
          int o4 = r * 64 + cq;
          if (s == 0) {
            ac4[o4] = kv;
            float4 hv = h4[o4];
            yc4[o4] = make_float4(hv.x + 0.125f * kv.x, hv.y + 0.125f * kv.y,
                                  hv.z + 0.125f * kv.z, hv.w + 0.125f * kv.w);
          } else if (s == 1) {
            float4 a = ac4[o4];
            ac4[o4] = make_float4(a.x + 2.f * kv.x, a.y + 2.f * kv.y,
                                  a.z + 2.f * kv.z, a.w + 2.f * kv.w);
            float4 hv = h4[o4];
            yc4[o4] = make_float4(hv.x + 0.125f * kv.x, hv.y + 0.125f * kv.y,
                                  hv.z + 0.125f * kv.z, hv.w + 0.125f * kv.w);
          } else if (s == 2) {
            float4 a = ac4[o4];
            ac4[o4] = make_float4(a.x + 2.f * kv.x, a.y + 2.f * kv.y,
                                  a.z + 2.f * kv.z, a.w + 2.f * kv.w);
            float4 hv = h4[o4];
            yc4[o4] = make_float4(hv.x + 0.25f * kv.x, hv.y + 0.25f * kv.y,
                                  hv.z + 0.25f * kv.z, hv.w + 0.25f * kv.w);
          } else {
            float4 a = ac4[o4];
            float4 hv = h4[o4];
            const float c6 = 0.25f / 6.f;
            h4[o4] = make_float4(hv.x + c6 * (a.x + kv.x), hv.y + c6 * (a.y + kv.y),
                                 hv.z + c6 * (a.z + kv.z), hv.w + c6 * (a.w + kv.w));
          }
        }
        __syncthreads();
      }
    }

    // ===== heads
    // l1 partials: (cq 32, kc 16) -> pr[0..1024): [kc][r][cq32]
    {
      const int cq = tid & 31, kc = tid >> 5;
      float4 c0 = make_float4(0, 0, 0, 0), c1 = c0;
#pragma unroll 2
      for (int g = 0; g < 4; ++g) {
        int kg = kc * 4 + g;
        float4 w0 = l1w4[kg * 128 + 4 * cq + 0];
        float4 w1 = l1w4[kg * 128 + 4 * cq + 1];
        float4 w2 = l1w4[kg * 128 + 4 * cq + 2];
        float4 w3 = l1w4[kg * 128 + 4 * cq + 3];
        float4 y0 = h44[kg], y1 = h44[64 + kg];
        c0.x = fma4(c0.x, y0, w0); c0.y = fma4(c0.y, y0, w1);
        c0.z = fma4(c0.z, y0, w2); c0.w = fma4(c0.w, y0, w3);
        c1.x = fma4(c1.x, y1, w0); c1.y = fma4(c1.y, y1, w1);
        c1.z = fma4(c1.z, y1, w2); c1.w = fma4(c1.w, y1, w3);
      }
      pr4[(kc * 2 + 0) * 32 + cq] = c0;
      pr4[(kc * 2 + 1) * 32 + cq] = c1;
    }
    // sig1 partials: (cq 64, kc 8) -> pr[1024..2048): [kc][r][cq]
    {
      float4 d0 = make_float4(0, 0, 0, 0), d1 = d0;
#pragma unroll 2
      for (int g = 0; g < 8; ++g) {
        int kg = kc2 * 8 + g;
        float4 w0 = sw14[kg * 256 + 4 * cq2 + 0];
        float4 w1 = sw14[kg * 256 + 4 * cq2 + 1];
        float4 w2 = sw14[kg * 256 + 4 * cq2 + 2];
        float4 w3 = sw14[kg * 256 + 4 * cq2 + 3];
        float4 y0 = h44[kg], y1 = h44[64 + kg];
        d0.x = fma4(d0.x, y0, w0); d0.y = fma4(d0.y, y0, w1);
        d0.z = fma4(d0.z, y0, w2); d0.w = fma4(d0.w, y0, w3);
        d1.x = fma4(d1.x, y1, w0); d1.y = fma4(d1.y, y1, w1);
        d1.z = fma4(d1.z, y1, w2); d1.w = fma4(d1.w, y1, w3);
      }
      pr4[1024 + (kc2 * 2 + 0) * 64 + cq2] = d0;
      pr4[1024 + (kc2 * 2 + 1) * 64 + cq2] = d1;
    }
    __syncthreads();
    // head reduces: l1 on tid<128 (shfl over sub), sig on tid in [128,256)
    if (tid < 128) {
      const int r = tid >> 6, sub = (tid >> 5) & 1, cq = tid & 31;
      float4 v = pr4[(sub * 8 * 2 + r) * 32 + cq];
#pragma unroll
      for (int i = 1; i < 8; ++i)
        v = add4(v, pr4[((sub * 8 + i) * 2 + r) * 32 + cq]);
      v.x += __shfl_xor(v.x, 32); v.y += __shfl_xor(v.y, 32);
      v.z += __shfl_xor(v.z, 32); v.w += __shfl_xor(v.w, 32);
      if (sub == 0) {
        float4 b = l1b4[cq];
        l1o4[r * 32 + cq] = make_float4(fmaxf(v.x + b.x, 0.f), fmaxf(v.y + b.y, 0.f),
                                        fmaxf(v.z + b.z, 0.f), fmaxf(v.w + b.w, 0.f));
      }
    } else if (tid < 256) {
      const int t2 = tid - 128;
      const int r = t2 >> 6, cq = t2 & 63;
      float4 v = pr4[1024 + r * 64 + cq];
#pragma unroll
      for (int kc = 1; kc < 8; ++kc)
        v = add4(v, pr4[1024 + (kc * 2 + r) * 64 + cq]);
      sg4[r * 64 + cq] = tfast4(add4(v, sb14[cq]));
    }
    __syncthreads();
    // final dot-products: waves 0-1 -> mu rows, waves 2-3 -> sig rows
    if (wv < 2) {
      const int r = wv, c = ln & 31;
      float4 l = l1o4[r * 32 + c], w = muw4[c];
      float pm = (ln < 32) ? (l.x * w.x + l.y * w.y + l.z * w.z + l.w * w.w) : 0.f;
#pragma unroll
      for (int off = 32; off > 0; off >>= 1) pm += __shfl_down(pm, off);
      if (ln == 0) out[(size_t)(b0 + r) * 100 + t] = pm + mub;
    } else if (wv < 4) {
      const int r = wv - 2;
      float4 s4 = sg4[r * 64 + ln], w = sw24[ln];
      float ps = s4.x * w.x + s4.y * w.y + s4.z * w.z + s4.w * w.w;
#pragma unroll
      for (int off = 32; off > 0; off >>= 1) ps += __shfl_down(ps, off);
      if (ln == 0) {
        float z = ps + sb2;
        float sp = fmaxf(z, 0.f) + log1pf(expf(-fabsf(z)));
        out[(size_t)102400 + (size_t)(b0 + r) * 100 + t] = sp;
      }
    }
    // no barrier: next-step staging writes x4S/sclS, disjoint from l1o/sg;
    // first pr write next step is after the stage barrier.
  }
}

extern "C" void kernel_launch(void* const* d_in, const int* in_sizes, int n_in,
                              void* d_out, int out_size, void* d_ws, size_t ws_size,
                              hipStream_t stream) {
  const float* dt  = (const float*)d_in[0];
  const float* x   = (const float*)d_in[1];
  const float* Wih = (const float*)d_in[2];
  const float* bih = (const float*)d_in[3];
  const float* Whh = (const float*)d_in[4];
  const float* bhh = (const float*)d_in[5];
  const float* ow1 = (const float*)d_in[6];
  const float* ob1 = (const float*)d_in[7];
  const float* ow2 = (const float*)d_in[8];
  const float* ob2 = (const float*)d_in[9];
  const float* l1w = (const float*)d_in[10];
  const float* l1b = (const float*)d_in[11];
  const float* muw = (const float*)d_in[12];
  const float* mub = (const float*)d_in[13];
  const float* sw1 = (const float*)d_in[14];
  const float* sb1 = (const float*)d_in[15];
  const float* sw2 = (const float*)d_in[16];
  const float* sb2 = (const float*)d_in[17];
  float* ws  = (float*)d_ws;
  float* out = (float*)d_out;

  hipFuncSetAttribute((const void*)odernn_main,
                      hipFuncAttributeMaxDynamicSharedMemorySize, SMEM_BYTES);

  prep_transpose<<<WS_TOT / 256, 256, 0, stream>>>(Wih, Whh, l1w, sw1, ws);
  odernn_main<<<512, NT, SMEM_BYTES, stream>>>(dt, x, bih, bhh, ow1, ob1, ow2, ob2,
                                               l1b, muw, mub, sb1, sw2, sb2, ws, out);
}